// Round 3
// baseline (142.292 us; speedup 1.0000x reference)
//
#include <hip/hip_runtime.h>

#define BI 128
#define BH 256
#define MT 32
#define NT 256

using f32x4  = __attribute__((ext_vector_type(4))) float;
using short8 = __attribute__((ext_vector_type(8))) short;

// ---------- bf16 helpers (RNE) ----------
__device__ __forceinline__ unsigned short f2bf(float f) {
  unsigned u = __float_as_uint(f);
  u = (u + 0x7FFFu + ((u >> 16) & 1u)) >> 16;
  return (unsigned short)u;
}
__device__ __forceinline__ float bf2f(unsigned short h) {
  return __uint_as_float(((unsigned)h) << 16);
}
__device__ __forceinline__ float fast_tanh(float v) {
  return 1.f - 2.f / (1.f + __expf(2.f * v));
}
__device__ __forceinline__ float fast_sigmoid(float v) {
  return 1.f / (1.f + __expf(-v));
}

// ---------- weight packing: W (HxK row-major f32) -> bf16 in B-fragment order ----------
__global__ void pack_w(const float* __restrict__ W, unsigned short* __restrict__ dst,
                       int K, int total) {
  int t = blockIdx.x * blockDim.x + threadIdx.x;
  if (t >= total) return;
  int lane = t & 63;
  int tile = t >> 6;
  int KT = K >> 5;
  int nf = tile / KT, kt = tile - nf * KT;
  int n  = nf * 16 + (lane & 15);
  int k0 = kt * 32 + (lane >> 4) * 8;
  const float* src = W + (size_t)n * K + k0;
#pragma unroll
  for (int j = 0; j < 8; ++j) dst[(size_t)t * 8 + j] = f2bf(src[j]);
}

// LDS layout (bytes), total 32896 -> 4 blocks/CU:
//     0 : h_bf  [32][256] bf16, XOR-swizzled rows (16384)
// 16384 : ha_bf [32][256] bf16, XOR-swizzled rows (16384)
// 32768 : ew[32] f32 (128)
__global__ __launch_bounds__(NT, 4) void liquid_kernel(
    const float* __restrict__ x, const float* __restrict__ prev,
    const float* __restrict__ hidden,
    const float* __restrict__ w_in_b, const float* __restrict__ w_rec_b,
    const float* __restrict__ attn_b,
    const float* __restrict__ ev_w, const float* __restrict__ ev_b,
    const float* __restrict__ tau,
    const unsigned short* __restrict__ win_p, const unsigned short* __restrict__ attn_p,
    const unsigned short* __restrict__ wrec_p,
    float* __restrict__ out, int Bn) {
  extern __shared__ char smem[];
  const int tid = threadIdx.x;
  const int lane = tid & 63;
  const int wid = tid >> 6;
  const int r0 = blockIdx.x * MT;
  const int lrow = lane & 15;
  const int lk = lane >> 4;

  // ---- stage hidden (32x256) as bf16, swizzled ----
#pragma unroll
  for (int it = 0; it < 8; ++it) {
    int idx4 = it * NT + tid;
    int row = idx4 >> 6;
    int c8 = (idx4 & 63) * 8;
    f32x4 v = *(const f32x4*)(hidden + (size_t)(r0 + row) * BH + (idx4 & 63) * 4);
    unsigned h01 = (unsigned)f2bf(v[0]) | ((unsigned)f2bf(v[1]) << 16);
    unsigned h23 = (unsigned)f2bf(v[2]) | ((unsigned)f2bf(v[3]) << 16);
    *(unsigned long long*)(smem + row * 512 + (c8 ^ ((row & 7) << 4))) =
        (unsigned long long)h01 | ((unsigned long long)h23 << 32);
  }

  // ---- event weight: 8 threads per row, f32 dot of 256 ----
  {
    int r = tid >> 3, p = tid & 7;
    float s = 0.f;
    const float* src = (p < 4) ? (x + (size_t)(r0 + r) * BI + p * 32)
                               : (prev + (size_t)(r0 + r) * BI + (p - 4) * 32);
    const float* wr = ev_w + p * 32;
#pragma unroll
    for (int i = 0; i < 8; ++i) {
      f32x4 a = *(const f32x4*)(src + i * 4);
      f32x4 w = *(const f32x4*)(wr + i * 4);
      s += a[0] * w[0] + a[1] * w[1] + a[2] * w[2] + a[3] * w[3];
    }
    s += __shfl_xor(s, 1);
    s += __shfl_xor(s, 2);
    s += __shfl_xor(s, 4);
    if (p == 0) {
      float ew = fast_sigmoid(s + ev_b[0]);
      *(float*)(smem + 32768 + r * 4) = ew;
      out[(size_t)Bn * BH + r0 + r] = ew;
    }
  }

  // ---- T14: issue epilogue hidden loads NOW (consumed ~2000 cyc later) ----
  float hreg[2][4][4];
#pragma unroll
  for (int mf = 0; mf < 2; ++mf)
#pragma unroll
    for (int j = 0; j < 4; ++j) {
      const float* hrow = hidden + (size_t)(r0 + mf * 16 + lk * 4 + j) * BH;
#pragma unroll
      for (int nf = 0; nf < 4; ++nf)
        hreg[mf][nf][j] = hrow[wid * 64 + nf * 16 + lrow];
    }
  asm volatile("" ::: "memory");  // pin: h loads issue before GEMM B-loads
  __syncthreads();

  // ---- GEMM2: attn preact = hidden @ attn_w^T (A from LDS, B from L2) ----
  f32x4 acc[2][4] = {};
  {
    const short8* bW = (const short8*)attn_p;
#pragma unroll
    for (int kt = 0; kt < 8; ++kt) {
      short8 ah[2];
#pragma unroll
      for (int mf = 0; mf < 2; ++mf) {
        int row = mf * 16 + lrow;
        ah[mf] = *(const short8*)(smem + row * 512 + ((kt * 64 + lk * 16) ^ ((row & 7) << 4)));
      }
#pragma unroll
      for (int nf = 0; nf < 4; ++nf) {
        short8 b = bW[((wid * 4 + nf) * 8 + kt) * 64 + lane];
#pragma unroll
        for (int mf = 0; mf < 2; ++mf)
          acc[mf][nf] = __builtin_amdgcn_mfma_f32_16x16x32_bf16(ah[mf], b, acc[mf][nf], 0, 0, 0);
      }
    }
  }

  // ---- aw = sigmoid(+b); ha = h * aw -> LDS bf16 ----
#pragma unroll
  for (int nf = 0; nf < 4; ++nf) {
    int col = wid * 64 + nf * 16 + lrow;
    float bb = attn_b[col];
#pragma unroll
    for (int mf = 0; mf < 2; ++mf) {
#pragma unroll
      for (int j = 0; j < 4; ++j) {
        int row = mf * 16 + lk * 4 + j;
        float aw = fast_sigmoid(acc[mf][nf][j] + bb);
        int hoff = row * 512 + ((col * 2) ^ ((row & 7) << 4));
        *(unsigned short*)(smem + 16384 + hoff) = f2bf(hreg[mf][nf][j] * aw);
      }
    }
  }

  // ---- GEMM1: ic = tanh(x @ W_in^T + b) (A from global, L1/L2-warm) ----
  f32x4 ic[2][4] = {};
  {
    const short8* bW = (const short8*)win_p;
#pragma unroll
    for (int kt = 0; kt < 4; ++kt) {
      short8 ax[2];
#pragma unroll
      for (int mf = 0; mf < 2; ++mf) {
        const float* xr = x + (size_t)(r0 + mf * 16 + lrow) * BI + kt * 32 + lk * 8;
        f32x4 a0 = *(const f32x4*)xr;
        f32x4 a1 = *(const f32x4*)(xr + 4);
        short8 t;
        t[0] = (short)f2bf(a0[0]); t[1] = (short)f2bf(a0[1]);
        t[2] = (short)f2bf(a0[2]); t[3] = (short)f2bf(a0[3]);
        t[4] = (short)f2bf(a1[0]); t[5] = (short)f2bf(a1[1]);
        t[6] = (short)f2bf(a1[2]); t[7] = (short)f2bf(a1[3]);
        ax[mf] = t;
      }
#pragma unroll
      for (int nf = 0; nf < 4; ++nf) {
        short8 b = bW[((wid * 4 + nf) * 4 + kt) * 64 + lane];
#pragma unroll
        for (int mf = 0; mf < 2; ++mf)
          ic[mf][nf] = __builtin_amdgcn_mfma_f32_16x16x32_bf16(ax[mf], b, ic[mf][nf], 0, 0, 0);
      }
    }
  }
#pragma unroll
  for (int nf = 0; nf < 4; ++nf) {
    float bb = w_in_b[wid * 64 + nf * 16 + lrow];
#pragma unroll
    for (int mf = 0; mf < 2; ++mf)
#pragma unroll
      for (int j = 0; j < 4; ++j)
        ic[mf][nf][j] = fast_tanh(ic[mf][nf][j] + bb);
  }
  __syncthreads();

  // ---- GEMM3: rec preact = ha @ W_rec^T ----
  f32x4 rcc[2][4] = {};
  {
    const short8* bW = (const short8*)wrec_p;
#pragma unroll
    for (int kt = 0; kt < 8; ++kt) {
      short8 ah[2];
#pragma unroll
      for (int mf = 0; mf < 2; ++mf) {
        int row = mf * 16 + lrow;
        ah[mf] = *(const short8*)(smem + 16384 + row * 512 +
                                  ((kt * 64 + lk * 16) ^ ((row & 7) << 4)));
      }
#pragma unroll
      for (int nf = 0; nf < 4; ++nf) {
        short8 b = bW[((wid * 4 + nf) * 8 + kt) * 64 + lane];
#pragma unroll
        for (int mf = 0; mf < 2; ++mf)
          rcc[mf][nf] = __builtin_amdgcn_mfma_f32_16x16x32_bf16(ah[mf], b, rcc[mf][nf], 0, 0, 0);
      }
    }
  }

  // ---- epilogue: new_h = h + dt/tau * (ic + rc - h) * (1 + ew) ----
  float brec[4], dtt[4];
#pragma unroll
  for (int nf = 0; nf < 4; ++nf) {
    int col = wid * 64 + nf * 16 + lrow;
    brec[nf] = w_rec_b[col];
    float t = tau[col];
    t = fminf(fmaxf(t, 0.1f), 10.f);
    dtt[nf] = 0.1f / t;
  }
#pragma unroll
  for (int mf = 0; mf < 2; ++mf) {
#pragma unroll
    for (int j = 0; j < 4; ++j) {
      int row = mf * 16 + lk * 4 + j;
      float e1 = 1.f + *(const float*)(smem + 32768 + row * 4);
      float* orow = out + (size_t)(r0 + row) * BH;
#pragma unroll
      for (int nf = 0; nf < 4; ++nf) {
        int col = wid * 64 + nf * 16 + lrow;
        float rc = fast_tanh(rcc[mf][nf][j] + brec[nf]);
        float h = hreg[mf][nf][j];
        orow[col] = h + dtt[nf] * (ic[mf][nf][j] + rc - h) * e1;
      }
    }
  }
}

extern "C" void kernel_launch(void* const* d_in, const int* in_sizes, int n_in,
                              void* d_out, int out_size, void* d_ws, size_t ws_size,
                              hipStream_t stream) {
  const float* x       = (const float*)d_in[0];
  const float* prev    = (const float*)d_in[1];
  const float* hidden  = (const float*)d_in[2];
  const float* W_in_w  = (const float*)d_in[3];
  const float* W_in_b  = (const float*)d_in[4];
  const float* W_rec_w = (const float*)d_in[5];
  const float* W_rec_b = (const float*)d_in[6];
  const float* attn_w  = (const float*)d_in[7];
  const float* attn_b  = (const float*)d_in[8];
  const float* ev_w    = (const float*)d_in[9];
  const float* ev_b    = (const float*)d_in[10];
  const float* tau     = (const float*)d_in[11];
  int Bn = in_sizes[0] / BI;

  unsigned short* ws = (unsigned short*)d_ws;
  unsigned short* win_p  = ws;             // 32768 elems
  unsigned short* attn_p = ws + 32768;     // 65536 elems
  unsigned short* wrec_p = ws + 98304;     // 65536 elems

  pack_w<<<(4096 + 255) / 256, 256, 0, stream>>>(W_in_w, win_p, BI, 4096);
  pack_w<<<(8192 + 255) / 256, 256, 0, stream>>>(attn_w, attn_p, BH, 8192);
  pack_w<<<(8192 + 255) / 256, 256, 0, stream>>>(W_rec_w, wrec_p, BH, 8192);

  liquid_kernel<<<Bn / MT, NT, 32896, stream>>>(
      x, prev, hidden, W_in_b, W_rec_b, attn_b, ev_w, ev_b, tau,
      win_p, attn_p, wrec_p, (float*)d_out, Bn);
}

// Round 4
// 111.854 us; speedup vs baseline: 1.2721x; 1.2721x over previous
//
#include <hip/hip_runtime.h>

#define BI 128
#define BH 256
#define MT 32
#define NT 256

using f32x4  = __attribute__((ext_vector_type(4))) float;
using short8 = __attribute__((ext_vector_type(8))) short;

// ---------- bf16 helpers (RNE) ----------
__device__ __forceinline__ unsigned short f2bf(float f) {
  unsigned u = __float_as_uint(f);
  u = (u + 0x7FFFu + ((u >> 16) & 1u)) >> 16;
  return (unsigned short)u;
}
__device__ __forceinline__ float bf2f(unsigned short h) {
  return __uint_as_float(((unsigned)h) << 16);
}
__device__ __forceinline__ float fast_tanh(float v) {
  return 1.f - 2.f / (1.f + __expf(2.f * v));
}
__device__ __forceinline__ float fast_sigmoid(float v) {
  return 1.f / (1.f + __expf(-v));
}

// ---------- weight packing: W (HxK row-major f32) -> bf16 in B-fragment order ----------
__global__ void pack_w(const float* __restrict__ W, unsigned short* __restrict__ dst,
                       int K, int total) {
  int t = blockIdx.x * blockDim.x + threadIdx.x;
  if (t >= total) return;
  int lane = t & 63;
  int tile = t >> 6;
  int KT = K >> 5;
  int nf = tile / KT, kt = tile - nf * KT;
  int n  = nf * 16 + (lane & 15);
  int k0 = kt * 32 + (lane >> 4) * 8;
  const float* src = W + (size_t)n * K + k0;
#pragma unroll
  for (int j = 0; j < 8; ++j) dst[(size_t)t * 8 + j] = f2bf(src[j]);
}

// LDS layout (bytes), total 32896 -> 4 blocks/CU:
//     0 : h_bf  [32][256] bf16, XOR-swizzled rows (16384)
// 16384 : ha_bf [32][256] bf16, XOR-swizzled rows (16384)
// 32768 : ew[32] f32 (128)
// After GEMM3, regions h/ha are overlaid with s[32][256] f32 (swizzled, 32768 B).
__global__ __launch_bounds__(NT, 2) void liquid_kernel(
    const float* __restrict__ x, const float* __restrict__ prev,
    const float* __restrict__ hidden,
    const float* __restrict__ w_in_b, const float* __restrict__ w_rec_b,
    const float* __restrict__ attn_b,
    const float* __restrict__ ev_w, const float* __restrict__ ev_b,
    const float* __restrict__ tau,
    const unsigned short* __restrict__ win_p, const unsigned short* __restrict__ attn_p,
    const unsigned short* __restrict__ wrec_p,
    float* __restrict__ out, int Bn) {
  extern __shared__ char smem[];
  const int tid = threadIdx.x;
  const int lane = tid & 63;
  const int wid = tid >> 6;
  const int r0 = blockIdx.x * MT;
  const int lrow = lane & 15;
  const int lk = lane >> 4;

  // ---- stage hidden (32x256) as bf16, swizzled ----
#pragma unroll
  for (int it = 0; it < 8; ++it) {
    int idx4 = it * NT + tid;
    int row = idx4 >> 6;
    int c8 = (idx4 & 63) * 8;
    f32x4 v = *(const f32x4*)(hidden + (size_t)(r0 + row) * BH + (idx4 & 63) * 4);
    unsigned h01 = (unsigned)f2bf(v[0]) | ((unsigned)f2bf(v[1]) << 16);
    unsigned h23 = (unsigned)f2bf(v[2]) | ((unsigned)f2bf(v[3]) << 16);
    *(unsigned long long*)(smem + row * 512 + (c8 ^ ((row & 7) << 4))) =
        (unsigned long long)h01 | ((unsigned long long)h23 << 32);
  }

  // ---- event weight: 8 threads per row, f32 dot of 256 ----
  {
    int r = tid >> 3, p = tid & 7;
    float s = 0.f;
    const float* src = (p < 4) ? (x + (size_t)(r0 + r) * BI + p * 32)
                               : (prev + (size_t)(r0 + r) * BI + (p - 4) * 32);
    const float* wr = ev_w + p * 32;
#pragma unroll
    for (int i = 0; i < 8; ++i) {
      f32x4 a = *(const f32x4*)(src + i * 4);
      f32x4 w = *(const f32x4*)(wr + i * 4);
      s += a[0] * w[0] + a[1] * w[1] + a[2] * w[2] + a[3] * w[3];
    }
    s += __shfl_xor(s, 1);
    s += __shfl_xor(s, 2);
    s += __shfl_xor(s, 4);
    if (p == 0) {
      float ew = fast_sigmoid(s + ev_b[0]);
      *(float*)(smem + 32768 + r * 4) = ew;
      out[(size_t)Bn * BH + r0 + r] = ew;
    }
  }
  __syncthreads();

  // ---- GEMM2: attn preact = hidden @ attn_w^T (A from LDS, B from L2) ----
  f32x4 acc[2][4] = {};
  {
    const short8* bW = (const short8*)attn_p;
#pragma unroll
    for (int kt = 0; kt < 8; ++kt) {
      short8 ah[2];
#pragma unroll
      for (int mf = 0; mf < 2; ++mf) {
        int row = mf * 16 + lrow;
        ah[mf] = *(const short8*)(smem + row * 512 + ((kt * 64 + lk * 16) ^ ((row & 7) << 4)));
      }
#pragma unroll
      for (int nf = 0; nf < 4; ++nf) {
        short8 b = bW[((wid * 4 + nf) * 8 + kt) * 64 + lane];
#pragma unroll
        for (int mf = 0; mf < 2; ++mf)
          acc[mf][nf] = __builtin_amdgcn_mfma_f32_16x16x32_bf16(ah[mf], b, acc[mf][nf], 0, 0, 0);
      }
    }
  }

  // ---- aw = sigmoid(+b); ha = h * aw -> LDS bf16 ----
#pragma unroll
  for (int nf = 0; nf < 4; ++nf) {
    int col = wid * 64 + nf * 16 + lrow;
    float bb = attn_b[col];
#pragma unroll
    for (int mf = 0; mf < 2; ++mf) {
#pragma unroll
      for (int j = 0; j < 4; ++j) {
        int row = mf * 16 + lk * 4 + j;
        float aw = fast_sigmoid(acc[mf][nf][j] + bb);
        int hoff = row * 512 + ((col * 2) ^ ((row & 7) << 4));
        float h = bf2f(*(const unsigned short*)(smem + hoff));
        *(unsigned short*)(smem + 16384 + hoff) = f2bf(h * aw);
      }
    }
  }

  // ---- GEMM1: ic = tanh(x @ W_in^T + b) (A from global, L1-warm) ----
  f32x4 ic[2][4] = {};
  {
    const short8* bW = (const short8*)win_p;
#pragma unroll
    for (int kt = 0; kt < 4; ++kt) {
      short8 ax[2];
#pragma unroll
      for (int mf = 0; mf < 2; ++mf) {
        const float* xr = x + (size_t)(r0 + mf * 16 + lrow) * BI + kt * 32 + lk * 8;
        f32x4 a0 = *(const f32x4*)xr;
        f32x4 a1 = *(const f32x4*)(xr + 4);
        short8 t;
        t[0] = (short)f2bf(a0[0]); t[1] = (short)f2bf(a0[1]);
        t[2] = (short)f2bf(a0[2]); t[3] = (short)f2bf(a0[3]);
        t[4] = (short)f2bf(a1[0]); t[5] = (short)f2bf(a1[1]);
        t[6] = (short)f2bf(a1[2]); t[7] = (short)f2bf(a1[3]);
        ax[mf] = t;
      }
#pragma unroll
      for (int nf = 0; nf < 4; ++nf) {
        short8 b = bW[((wid * 4 + nf) * 4 + kt) * 64 + lane];
#pragma unroll
        for (int mf = 0; mf < 2; ++mf)
          ic[mf][nf] = __builtin_amdgcn_mfma_f32_16x16x32_bf16(ax[mf], b, ic[mf][nf], 0, 0, 0);
      }
    }
  }
#pragma unroll
  for (int nf = 0; nf < 4; ++nf) {
    float bb = w_in_b[wid * 64 + nf * 16 + lrow];
#pragma unroll
    for (int mf = 0; mf < 2; ++mf)
#pragma unroll
      for (int j = 0; j < 4; ++j)
        ic[mf][nf][j] = fast_tanh(ic[mf][nf][j] + bb);
  }
  __syncthreads();

  // ---- GEMM3: rec preact = ha @ W_rec^T ----
  f32x4 rcc[2][4] = {};
  {
    const short8* bW = (const short8*)wrec_p;
#pragma unroll
    for (int kt = 0; kt < 8; ++kt) {
      short8 ah[2];
#pragma unroll
      for (int mf = 0; mf < 2; ++mf) {
        int row = mf * 16 + lrow;
        ah[mf] = *(const short8*)(smem + 16384 + row * 512 +
                                  ((kt * 64 + lk * 16) ^ ((row & 7) << 4)));
      }
#pragma unroll
      for (int nf = 0; nf < 4; ++nf) {
        short8 b = bW[((wid * 4 + nf) * 8 + kt) * 64 + lane];
#pragma unroll
        for (int mf = 0; mf < 2; ++mf)
          rcc[mf][nf] = __builtin_amdgcn_mfma_f32_16x16x32_bf16(ah[mf], b, rcc[mf][nf], 0, 0, 0);
      }
    }
  }

  // ---- s = ic + tanh(rcc + brec) -> LDS f32 overlay (h/ha regions dead) ----
  __syncthreads();  // all waves done reading ha
#pragma unroll
  for (int nf = 0; nf < 4; ++nf) {
    int col = wid * 64 + nf * 16 + lrow;
    float brec = w_rec_b[col];
#pragma unroll
    for (int mf = 0; mf < 2; ++mf) {
#pragma unroll
      for (int j = 0; j < 4; ++j) {
        int row = mf * 16 + lk * 4 + j;
        float s = ic[mf][nf][j] + fast_tanh(rcc[mf][nf][j] + brec);
        *(float*)(smem + row * 1024 + ((col * 4) ^ ((row & 7) << 4))) = s;
      }
    }
  }
  __syncthreads();

  // ---- final coalesced pass: out = h + dt/tau * (s - h) * (1 + ew) ----
  {
    f32x4 t4 = *(const f32x4*)(tau + lane * 4);
    f32x4 dtt;
#pragma unroll
    for (int i = 0; i < 4; ++i) {
      float t = fminf(fmaxf(t4[i], 0.1f), 10.f);
      dtt[i] = 0.1f / t;
    }
#pragma unroll
    for (int it = 0; it < 8; ++it) {
      int row = it * 4 + wid;
      float e1 = 1.f + *(const float*)(smem + 32768 + row * 4);
      f32x4 s4 = *(const f32x4*)(smem + row * 1024 + ((lane * 16) ^ ((row & 7) << 4)));
      f32x4 h4 = *(const f32x4*)(hidden + (size_t)(r0 + row) * BH + lane * 4);
      f32x4 o;
#pragma unroll
      for (int i = 0; i < 4; ++i)
        o[i] = h4[i] + dtt[i] * (s4[i] - h4[i]) * e1;
      *(f32x4*)(out + (size_t)(r0 + row) * BH + lane * 4) = o;
    }
  }
}

extern "C" void kernel_launch(void* const* d_in, const int* in_sizes, int n_in,
                              void* d_out, int out_size, void* d_ws, size_t ws_size,
                              hipStream_t stream) {
  const float* x       = (const float*)d_in[0];
  const float* prev    = (const float*)d_in[1];
  const float* hidden  = (const float*)d_in[2];
  const float* W_in_w  = (const float*)d_in[3];
  const float* W_in_b  = (const float*)d_in[4];
  const float* W_rec_w = (const float*)d_in[5];
  const float* W_rec_b = (const float*)d_in[6];
  const float* attn_w  = (const float*)d_in[7];
  const float* attn_b  = (const float*)d_in[8];
  const float* ev_w    = (const float*)d_in[9];
  const float* ev_b    = (const float*)d_in[10];
  const float* tau     = (const float*)d_in[11];
  int Bn = in_sizes[0] / BI;

  unsigned short* ws = (unsigned short*)d_ws;
  unsigned short* win_p  = ws;             // 32768 elems
  unsigned short* attn_p = ws + 32768;     // 65536 elems
  unsigned short* wrec_p = ws + 98304;     // 65536 elems

  pack_w<<<(4096 + 255) / 256, 256, 0, stream>>>(W_in_w, win_p, BI, 4096);
  pack_w<<<(8192 + 255) / 256, 256, 0, stream>>>(attn_w, attn_p, BH, 8192);
  pack_w<<<(8192 + 255) / 256, 256, 0, stream>>>(W_rec_w, wrec_p, BH, 8192);

  liquid_kernel<<<Bn / MT, NT, 32896, stream>>>(
      x, prev, hidden, W_in_b, W_rec_b, attn_b, ev_w, ev_b, tau,
      win_p, attn_p, wrec_p, (float*)d_out, Bn);
}